// Round 1
// baseline (91.638 us; speedup 1.0000x reference)
//
#include <hip/hip_runtime.h>
#include <hip/hip_bf16.h>

// Depthwise 4x4 binomial blur + stride-2 downsample.
// kernel = outer([1,3,3,1],[1,3,3,1]) / 64  -> separable: [1,3,3,1]/8 twice.
// Input  (B*C, 256, 256) fp32, output (B*C, 128, 128) fp32, pad=1.

#define IN_H 256
#define IN_W 256
#define OUT_H 128
#define OUT_W 128
#define OH_TILE 16
#define NROWS (2 * OH_TILE + 2)  // 34 intermediate (h-filtered) rows per tile

__global__ __launch_bounds__(256) void downsample_kernel(
    const float* __restrict__ x, float* __restrict__ y) {
    // h[r][ow]: horizontally filtered rows, r local in [0, NROWS)
    __shared__ float h[NROWS][OUT_W];  // 34*128*4 = 17408 B

    const int plane = blockIdx.y;                 // b*C + c
    const int oh0   = blockIdx.x * OH_TILE;       // first output row of tile
    const float* __restrict__ xp = x + (size_t)plane * IN_H * IN_W;
    float* __restrict__ yp       = y + (size_t)plane * OUT_H * OUT_W;
    const int r0 = 2 * oh0 - 1;                   // first needed input row (may be -1)

    // ---- Horizontal pass: global -> LDS ----
    // item -> (local row lr, output col ow). 34*128 = 4352 items, 256 threads -> 17 iters.
    for (int item = threadIdx.x; item < NROWS * OUT_W; item += 256) {
        const int lr = item >> 7;       // item / 128
        const int ow = item & 127;      // item % 128
        const int r  = r0 + lr;
        float v = 0.0f;
        if (r >= 0 && r < IN_H) {
            const float* __restrict__ row = xp + (size_t)r * IN_W;
            const int c0 = 2 * ow - 1;  // in [-1, 253]
            // c0+1 in [0,254] and c0+2 in [1,255] are always in-bounds.
            const float a = (c0 >= 0)       ? row[c0]     : 0.0f;
            const float b = row[c0 + 1];
            const float c = row[c0 + 2];
            const float d = (c0 + 3 < IN_W) ? row[c0 + 3] : 0.0f;
            v = (a + 3.0f * b + 3.0f * c + d) * 0.125f;
        }
        h[lr][ow] = v;
    }
    __syncthreads();

    // ---- Vertical pass: LDS -> global ----
    // 16 output rows * 128 cols = 2048 items, 256 threads -> 8 iters.
    for (int item = threadIdx.x; item < OH_TILE * OUT_W; item += 256) {
        const int ol = item >> 7;
        const int ow = item & 127;
        const int base = 2 * ol;  // local h-row for tap k=0
        const float v = (h[base][ow] + 3.0f * h[base + 1][ow] +
                         3.0f * h[base + 2][ow] + h[base + 3][ow]) * 0.125f;
        yp[(size_t)(oh0 + ol) * OUT_W + ow] = v;
    }
}

extern "C" void kernel_launch(void* const* d_in, const int* in_sizes, int n_in,
                              void* d_out, int out_size, void* d_ws, size_t ws_size,
                              hipStream_t stream) {
    (void)n_in; (void)d_ws; (void)ws_size; (void)out_size;
    const float* x = (const float*)d_in[0];
    float* y = (float*)d_out;
    const int planes = in_sizes[0] / (IN_H * IN_W);   // B*C = 1024
    dim3 grid(OUT_H / OH_TILE, planes);               // (8, 1024)
    dim3 block(256);
    downsample_kernel<<<grid, block, 0, stream>>>(x, y);
}

// Round 2
// 67.297 us; speedup vs baseline: 1.3617x; 1.3617x over previous
//
#include <hip/hip_runtime.h>
#include <hip/hip_bf16.h>

// Depthwise 4x4 binomial blur + stride-2 downsample, separable [1,3,3,1]/8 x2.
// Input (B*C, 256, 256) fp32 -> output (B*C, 128, 128) fp32, pad=1.
//
// One wave loads ONE full input row per iteration: 64 lanes x float4 = 256
// floats. Horizontal halo (x[4l-1], x[4l+4]) comes from neighbor lanes via
// shuffles; lanes 0/63 are the true row edges (zero pad). Each lane emits 2
// h-filtered values -> float2 LDS write (2-way bank alias = free).

#define IN_H 256
#define IN_W 256
#define OUT_H 128
#define OUT_W 128
#define OH_TILE 16
#define NROWS (2 * OH_TILE + 2)  // 34 h-filtered rows per tile

__global__ __launch_bounds__(256) void downsample_kernel(
    const float* __restrict__ x, float* __restrict__ y) {
    __shared__ float h[NROWS][OUT_W];  // 34*128*4 = 17408 B -> 8 blocks/CU fits

    const int plane = blockIdx.y;
    const int oh0   = blockIdx.x * OH_TILE;
    const float* __restrict__ xp = x + (size_t)plane * IN_H * IN_W;
    float* __restrict__ yp       = y + (size_t)plane * OUT_H * OUT_W;
    const int r0   = 2 * oh0 - 1;          // first needed input row (may be -1/256)
    const int lane = threadIdx.x & 63;
    const int wid  = threadIdx.x >> 6;     // 4 waves/block

    // ---- Horizontal pass: one wave per row, wave-uniform row index ----
    #pragma unroll
    for (int lr = 0; lr < NROWS; lr += 4) {
        const int myr = lr + wid;
        if (myr >= NROWS) break;           // only the lr=32 tail (waves 2,3 idle)
        const int r = r0 + myr;
        float2 o;
        if (r >= 0 && r < IN_H) {          // wave-uniform branch
            const float4 v = *(const float4*)(xp + (size_t)r * IN_W + 4 * lane);
            float prev = __shfl_up(v.w, 1);    // x[4l-1]
            float next = __shfl_down(v.x, 1);  // x[4l+4]
            if (lane == 0)  prev = 0.0f;       // left zero-pad
            if (lane == 63) next = 0.0f;       // right zero-pad
            o.x = (prev + 3.0f * v.x + 3.0f * v.y + v.z) * 0.125f;  // ow = 2l
            o.y = (v.y + 3.0f * v.z + 3.0f * v.w + next) * 0.125f;  // ow = 2l+1
        } else {
            o.x = 0.0f; o.y = 0.0f;        // top/bottom zero-pad rows
        }
        *(float2*)(&h[myr][2 * lane]) = o;
    }
    __syncthreads();

    // ---- Vertical pass: float4 per thread, 16 rows x 32 quads = 512 items ----
    #pragma unroll
    for (int it = 0; it < 2; ++it) {
        const int item = threadIdx.x + it * 256;
        const int ol   = item >> 5;
        const int c4   = (item & 31) * 4;
        const int base = 2 * ol;
        const float4 a = *(const float4*)&h[base][c4];
        const float4 b = *(const float4*)&h[base + 1][c4];
        const float4 c = *(const float4*)&h[base + 2][c4];
        const float4 d = *(const float4*)&h[base + 3][c4];
        float4 o;
        o.x = (a.x + 3.0f * b.x + 3.0f * c.x + d.x) * 0.125f;
        o.y = (a.y + 3.0f * b.y + 3.0f * c.y + d.y) * 0.125f;
        o.z = (a.z + 3.0f * b.z + 3.0f * c.z + d.z) * 0.125f;
        o.w = (a.w + 3.0f * b.w + 3.0f * c.w + d.w) * 0.125f;
        *(float4*)(yp + (size_t)(oh0 + ol) * OUT_W + c4) = o;
    }
}

extern "C" void kernel_launch(void* const* d_in, const int* in_sizes, int n_in,
                              void* d_out, int out_size, void* d_ws, size_t ws_size,
                              hipStream_t stream) {
    (void)n_in; (void)d_ws; (void)ws_size; (void)out_size;
    const float* x = (const float*)d_in[0];
    float* y = (float*)d_out;
    const int planes = in_sizes[0] / (IN_H * IN_W);   // B*C = 1024
    dim3 grid(OUT_H / OH_TILE, planes);               // (8, 1024)
    dim3 block(256);
    downsample_kernel<<<grid, block, 0, stream>>>(x, y);
}

// Round 3
// 63.924 us; speedup vs baseline: 1.4335x; 1.0528x over previous
//
#include <hip/hip_runtime.h>
#include <hip/hip_bf16.h>

// Depthwise 4x4 binomial blur + stride-2 downsample, separable [1,3,3,1] x2, /64.
// Input (B*C, 256, 256) fp32 -> output (B*C, 128, 128) fp32, pad=1.
//
// Barrier-free, LDS-free: one wave produces an output ROW-PAIR (rows 2p, 2p+1),
// reading the 6 input rows 4p-1..4p+4. Each row is one wave-wide float4 load
// (64 lanes x 16 B = the whole 256-float row). Horizontal [1,3,3,1] taps use
// 2 lane-shuffles per row; vertical combine stays in registers. Adjacent
// waves/blocks re-read 2 overlap rows -> absorbed by L1/L2, so HBM fetch is
// the ideal 268 MB.

#define IN_H 256
#define IN_W 256
#define OUT_H 128
#define OUT_W 128

__global__ __launch_bounds__(256) void downsample_kernel(
    const float* __restrict__ x, float* __restrict__ y) {
    const int plane = blockIdx.y;
    const int p     = blockIdx.x * 4 + (threadIdx.x >> 6);  // row-pair idx 0..63
    const int lane  = threadIdx.x & 63;
    const float* __restrict__ xp = x + (size_t)plane * IN_H * IN_W;

    // h[k][j]: horizontally filtered value at input row 4p-1+k, output col 2*lane+j
    float h[6][2];
    #pragma unroll
    for (int k = 0; k < 6; ++k) {
        const int r = 4 * p - 1 + k;
        if (r < 0 || r >= IN_H) {            // wave-uniform (p uniform per wave)
            h[k][0] = 0.0f; h[k][1] = 0.0f;
            continue;
        }
        const float4 v = *(const float4*)(xp + (size_t)r * IN_W + 4 * lane);
        float prev = __shfl_up(v.w, 1);      // x[4l-1]
        float next = __shfl_down(v.x, 1);    // x[4l+4]
        if (lane == 0)  prev = 0.0f;         // left zero-pad
        if (lane == 63) next = 0.0f;         // right zero-pad
        h[k][0] = prev + 3.0f * v.x + 3.0f * v.y + v.z;
        h[k][1] = v.y + 3.0f * v.z + 3.0f * v.w + next;
    }

    // Vertical [1,3,3,1]; combined scale (1/8)*(1/8) = 1/64 applied once.
    const float s = 1.0f / 64.0f;
    float2 o0, o1;
    o0.x = (h[0][0] + 3.0f * h[1][0] + 3.0f * h[2][0] + h[3][0]) * s;
    o0.y = (h[0][1] + 3.0f * h[1][1] + 3.0f * h[2][1] + h[3][1]) * s;
    o1.x = (h[2][0] + 3.0f * h[3][0] + 3.0f * h[4][0] + h[5][0]) * s;
    o1.y = (h[2][1] + 3.0f * h[3][1] + 3.0f * h[4][1] + h[5][1]) * s;

    float* __restrict__ yp =
        y + (size_t)plane * OUT_H * OUT_W + (size_t)(2 * p) * OUT_W;
    *(float2*)(yp + 2 * lane)         = o0;   // output row 2p
    *(float2*)(yp + OUT_W + 2 * lane) = o1;   // output row 2p+1
}

extern "C" void kernel_launch(void* const* d_in, const int* in_sizes, int n_in,
                              void* d_out, int out_size, void* d_ws, size_t ws_size,
                              hipStream_t stream) {
    (void)n_in; (void)d_ws; (void)ws_size; (void)out_size;
    const float* x = (const float*)d_in[0];
    float* y = (float*)d_out;
    const int planes = in_sizes[0] / (IN_H * IN_W);   // B*C = 1024
    dim3 grid(16, planes);    // 16 blocks x 4 waves = 64 row-pairs = 128 rows
    dim3 block(256);
    downsample_kernel<<<grid, block, 0, stream>>>(x, y);
}